// Round 2
// baseline (169.634 us; speedup 1.0000x reference)
//
#include <hip/hip_runtime.h>
#include <hip/hip_bf16.h>

// Problem: out[b,m,o] = sum_i x[b,m,i] * w[m,i,o] + bias[m,o]
// B=4096, M=8, IN=512, OUT=512, all fp32.
// Strategy: per-mode GEMM via bf16 MFMA (no fp32 MFMA on CDNA4), fp32 accum.

#define B_   4096
#define M_   8
#define IN_  512
#define OUT_ 512
#define BM   64
#define BN   64
#define BK   32

typedef __attribute__((ext_vector_type(8))) short  short8;   // 8 bf16 (4 VGPRs)
typedef __attribute__((ext_vector_type(4))) float  f32x4;
typedef __attribute__((ext_vector_type(4))) int    i32x4;

// pack two floats into two RNE-rounded bf16 in one u32 (lo, hi)
static __device__ inline unsigned f2bf2(float lo, float hi) {
  union { float f; unsigned u; } a, b;
  a.f = lo; b.f = hi;
  unsigned ua = a.u + 0x7FFFu + ((a.u >> 16) & 1u);
  unsigned ub = b.u + 0x7FFFu + ((b.u >> 16) & 1u);
  return (ua >> 16) | (ub & 0xFFFF0000u);
}

extern "C" __global__ __launch_bounds__(256, 2)
void mmlin_kernel(const float* __restrict__ X, const float* __restrict__ W,
                  const float* __restrict__ Bias, float* __restrict__ O) {
  // LDS: A tile [BM=64][BK=32] bf16 at 0..4095, W^T tile [col=64][k=32] bf16 at 4096..8191.
  // Both XOR-swizzled: byte_addr ^= ((row & 7) << 4)  (rows stride 64B).
  __shared__ unsigned char lds[8192];

  const int t    = threadIdx.x;
  const int lane = t & 63;
  const int w    = t >> 6;

  const int b0 = blockIdx.x * BM;
  const int n0 = blockIdx.y * BN;
  const int m  = blockIdx.z;

  // ---- staging: A (X tile). thread t: row = t>>2 (0..63), k0 = (t&3)*8.
  const int ar  = t >> 2;
  const int ak0 = (t & 3) * 8;
  const float* aptr = X + (size_t)(b0 + ar) * (M_ * IN_) + m * IN_ + ak0;
  const int a_st = (ar * 64 + ak0 * 2) ^ ((ar & 7) << 4);

  // ---- staging: B (W tile, stored transposed [col][k]).
  // thread t: col = t&63, k0 = (t>>6)*8. Global reads coalesced across lanes (col contiguous).
  const int bc  = t & 63;
  const int bk0 = (t >> 6) * 8;
  const float* bptr = W + (size_t)m * IN_ * OUT_ + (size_t)bk0 * OUT_ + n0 + bc;
  const int b_st = (4096 + bc * 64 + bk0 * 2) ^ ((bc & 7) << 4);

  // ---- MFMA fragment read addresses.
  // A frag: lane holds A[row = wr+mi*16+(lane&15)][k = (lane>>4)*8 + j], j=0..7
  // B frag: lane holds B[k][col = wc+ni*16+(lane&15)]  -> lds_b[col][k], same pattern.
  const int wr  = (w >> 1) * 32;
  const int wc  = (w & 1) * 32;
  const int fr  = lane & 15;
  const int fkB = (lane >> 4) * 16;   // byte offset of this lane's 8-elem k slot

  int a_ld[2], b_ld[2];
#pragma unroll
  for (int mi = 0; mi < 2; ++mi) {
    int row = wr + mi * 16 + fr;
    a_ld[mi] = (row * 64 + fkB) ^ ((row & 7) << 4);
  }
#pragma unroll
  for (int ni = 0; ni < 2; ++ni) {
    int col = wc + ni * 16 + fr;
    b_ld[ni] = (4096 + col * 64 + fkB) ^ ((col & 7) << 4);
  }

  f32x4 acc[2][2] = {};

  for (int kk = 0; kk < IN_; kk += BK) {
    // issue global loads (fp32)
    const f32x4* ap = (const f32x4*)(aptr + kk);
    f32x4 av0 = ap[0];
    f32x4 av1 = ap[1];
    float bv[8];
#pragma unroll
    for (int j = 0; j < 8; ++j) bv[j] = bptr[(kk + j) * OUT_];

    __syncthreads();   // prior iteration's LDS reads complete

    // convert + store to LDS
    i32x4 apk, bpk;
    apk[0] = f2bf2(av0[0], av0[1]);
    apk[1] = f2bf2(av0[2], av0[3]);
    apk[2] = f2bf2(av1[0], av1[1]);
    apk[3] = f2bf2(av1[2], av1[3]);
    bpk[0] = f2bf2(bv[0], bv[1]);
    bpk[1] = f2bf2(bv[2], bv[3]);
    bpk[2] = f2bf2(bv[4], bv[5]);
    bpk[3] = f2bf2(bv[6], bv[7]);
    *(i32x4*)(lds + a_st) = apk;
    *(i32x4*)(lds + b_st) = bpk;

    __syncthreads();   // tile visible to all waves

    short8 afrag[2], bfrag[2];
#pragma unroll
    for (int mi = 0; mi < 2; ++mi) afrag[mi] = *(const short8*)(lds + a_ld[mi]);
#pragma unroll
    for (int ni = 0; ni < 2; ++ni) bfrag[ni] = *(const short8*)(lds + b_ld[ni]);

#pragma unroll
    for (int mi = 0; mi < 2; ++mi)
#pragma unroll
      for (int ni = 0; ni < 2; ++ni)
        acc[mi][ni] = __builtin_amdgcn_mfma_f32_16x16x32_bf16(
            afrag[mi], bfrag[ni], acc[mi][ni], 0, 0, 0);
  }

  // ---- epilogue: D layout col = lane&15, row = (lane>>4)*4 + r
#pragma unroll
  for (int ni = 0; ni < 2; ++ni) {
    const int col = n0 + wc + ni * 16 + fr;
    const float bs = Bias[m * OUT_ + col];
#pragma unroll
    for (int mi = 0; mi < 2; ++mi) {
#pragma unroll
      for (int r = 0; r < 4; ++r) {
        const int row = b0 + wr + mi * 16 + (lane >> 4) * 4 + r;
        O[(size_t)row * (M_ * OUT_) + m * OUT_ + col] = acc[mi][ni][r] + bs;
      }
    }
  }
}

extern "C" void kernel_launch(void* const* d_in, const int* in_sizes, int n_in,
                              void* d_out, int out_size, void* d_ws, size_t ws_size,
                              hipStream_t stream) {
  const float* X    = (const float*)d_in[0];
  const float* W    = (const float*)d_in[1];
  const float* Bias = (const float*)d_in[2];
  float* O = (float*)d_out;

  dim3 grid(B_ / BM, OUT_ / BN, M_);
  mmlin_kernel<<<grid, dim3(256), 0, stream>>>(X, W, Bias, O);
}

// Round 3
// 158.359 us; speedup vs baseline: 1.0712x; 1.0712x over previous
//
#include <hip/hip_runtime.h>
#include <hip/hip_bf16.h>

// out[b,m,o] = sum_i x[b,m,i] * w[m,i,o] + bias[m,o]
// B=4096, M=8, IN=OUT=512, fp32. Per-mode GEMM via bf16 MFMA, fp32 accum.
// Round 2: 128x128 tile, BK=32, 4 waves x (4x4 16x16x32 frags),
// prefetch-next-K-tile after barrier (hide HBM latency under MFMA),
// convert fp32->bf16 after the MFMA block.

#define B_   4096
#define M_   8
#define IN_  512
#define OUT_ 512
#define BM   128
#define BN   128
#define BK   32

typedef __attribute__((ext_vector_type(8))) short  short8;   // 8 bf16
typedef __attribute__((ext_vector_type(4))) float  f32x4;
typedef __attribute__((ext_vector_type(4))) int    i32x4;

// pack two floats into two RNE-rounded bf16 in one u32 (lo, hi)
static __device__ inline unsigned f2bf2(float lo, float hi) {
  union { float f; unsigned u; } a, b;
  a.f = lo; b.f = hi;
  unsigned ua = a.u + 0x7FFFu + ((a.u >> 16) & 1u);
  unsigned ub = b.u + 0x7FFFu + ((b.u >> 16) & 1u);
  return (ua >> 16) | (ub & 0xFFFF0000u);
}

static __device__ inline i32x4 pack8(f32x4 u, f32x4 v) {
  i32x4 r;
  r[0] = f2bf2(u[0], u[1]);
  r[1] = f2bf2(u[2], u[3]);
  r[2] = f2bf2(v[0], v[1]);
  r[3] = f2bf2(v[2], v[3]);
  return r;
}

extern "C" __global__ __launch_bounds__(256, 2)
void mmlin_kernel(const float* __restrict__ X, const float* __restrict__ W,
                  const float* __restrict__ Bias, float* __restrict__ O) {
  // LDS: A [row 0..127][k 0..31] bf16 @0 (8KB, 64B row stride),
  //      B^T [col 0..127][k 0..31] bf16 @8192 (8KB).
  // Swizzle: phys = addr ^ ((row&7)<<4)  — bijective, conflict-free b128.
  __shared__ unsigned char lds[16384];

  const int t    = threadIdx.x;
  const int lane = t & 63;
  const int w    = t >> 6;

  const int b0 = blockIdx.x * BM;
  const int n0 = blockIdx.y * BN;
  const int m  = blockIdx.z;

  // ---- A staging: row = t>>1 (0..127), c0 = (t&1)*16 floats (64B half-row)
  const int ar  = t >> 1;
  const int ac0 = (t & 1) * 16;
  const float* aptr = X + (size_t)(b0 + ar) * (M_ * IN_) + m * IN_ + ac0;
  const int swzA  = (ar & 7) << 4;
  const int a_st0 = (ar * 64 + ac0 * 2)      ^ swzA;
  const int a_st1 = (ar * 64 + ac0 * 2 + 16) ^ swzA;

  // ---- B staging: col = t&127, k0 = (t>>7)*16 (16 k-rows each)
  const int bc  = t & 127;
  const int bk0 = (t >> 7) * 16;
  const float* bptr = W + (size_t)m * IN_ * OUT_ + (size_t)bk0 * OUT_ + n0 + bc;
  const int swzB  = (bc & 7) << 4;
  const int b_st0 = (8192 + bc * 64 + bk0 * 2)      ^ swzB;
  const int b_st1 = (8192 + bc * 64 + bk0 * 2 + 16) ^ swzB;

  // ---- fragment read addresses (wave tile 64x64, 4x4 16x16 frags)
  const int wr  = (w >> 1) * 64;
  const int wc  = (w & 1)  * 64;
  const int fr  = lane & 15;
  const int fkB = (lane >> 4) * 16;

  int a_ld[4], b_ld[4];
#pragma unroll
  for (int mi = 0; mi < 4; ++mi) {
    int row = wr + mi * 16 + fr;
    a_ld[mi] = (row * 64 + fkB) ^ ((row & 7) << 4);
  }
#pragma unroll
  for (int ni = 0; ni < 4; ++ni) {
    int col = wc + ni * 16 + fr;
    b_ld[ni] = (8192 + col * 64 + fkB) ^ ((col & 7) << 4);
  }

  f32x4 acc[4][4] = {};

  // ---- prologue: load + convert K-tile 0
  f32x4 a_raw[4];
  float b_raw[16];
  {
    const f32x4* ap = (const f32x4*)aptr;
#pragma unroll
    for (int i = 0; i < 4; ++i) a_raw[i] = ap[i];
#pragma unroll
    for (int j = 0; j < 16; ++j) b_raw[j] = bptr[(size_t)j * OUT_];
  }
  i32x4 apk0 = pack8(a_raw[0], a_raw[1]);
  i32x4 apk1 = pack8(a_raw[2], a_raw[3]);
  i32x4 bpk0, bpk1;
  bpk0[0] = f2bf2(b_raw[0],  b_raw[1]);  bpk0[1] = f2bf2(b_raw[2],  b_raw[3]);
  bpk0[2] = f2bf2(b_raw[4],  b_raw[5]);  bpk0[3] = f2bf2(b_raw[6],  b_raw[7]);
  bpk1[0] = f2bf2(b_raw[8],  b_raw[9]);  bpk1[1] = f2bf2(b_raw[10], b_raw[11]);
  bpk1[2] = f2bf2(b_raw[12], b_raw[13]); bpk1[3] = f2bf2(b_raw[14], b_raw[15]);

  for (int kk = 0; kk < IN_; kk += BK) {
    __syncthreads();                         // WAR: prior iter's LDS reads done
    *(i32x4*)(lds + a_st0) = apk0;
    *(i32x4*)(lds + a_st1) = apk1;
    *(i32x4*)(lds + b_st0) = bpk0;
    *(i32x4*)(lds + b_st1) = bpk1;
    __syncthreads();                         // RAW: tile visible

    const int kn = kk + BK;
    if (kn < IN_) {                          // issue next tile's loads NOW;
      const f32x4* ap = (const f32x4*)(aptr + kn);   // latency hides under MFMAs
#pragma unroll
      for (int i = 0; i < 4; ++i) a_raw[i] = ap[i];
#pragma unroll
      for (int j = 0; j < 16; ++j) b_raw[j] = bptr[(size_t)(kn + j) * OUT_];
    }

    short8 af[4], bf4[4];
#pragma unroll
    for (int mi = 0; mi < 4; ++mi) af[mi]  = *(const short8*)(lds + a_ld[mi]);
#pragma unroll
    for (int ni = 0; ni < 4; ++ni) bf4[ni] = *(const short8*)(lds + b_ld[ni]);

#pragma unroll
    for (int mi = 0; mi < 4; ++mi)
#pragma unroll
      for (int ni = 0; ni < 4; ++ni)
        acc[mi][ni] = __builtin_amdgcn_mfma_f32_16x16x32_bf16(
            af[mi], bf4[ni], acc[mi][ni], 0, 0, 0);

    if (kn < IN_) {                          // convert AFTER MFMAs (vmcnt lands here)
      apk0 = pack8(a_raw[0], a_raw[1]);
      apk1 = pack8(a_raw[2], a_raw[3]);
      bpk0[0] = f2bf2(b_raw[0],  b_raw[1]);  bpk0[1] = f2bf2(b_raw[2],  b_raw[3]);
      bpk0[2] = f2bf2(b_raw[4],  b_raw[5]);  bpk0[3] = f2bf2(b_raw[6],  b_raw[7]);
      bpk1[0] = f2bf2(b_raw[8],  b_raw[9]);  bpk1[1] = f2bf2(b_raw[10], b_raw[11]);
      bpk1[2] = f2bf2(b_raw[12], b_raw[13]); bpk1[3] = f2bf2(b_raw[14], b_raw[15]);
    }
  }

  // ---- epilogue: D layout col = lane&15, row = (lane>>4)*4 + r
#pragma unroll
  for (int ni = 0; ni < 4; ++ni) {
    const int col = n0 + wc + ni * 16 + fr;
    const float bs = Bias[m * OUT_ + col];
#pragma unroll
    for (int mi = 0; mi < 4; ++mi) {
#pragma unroll
      for (int r = 0; r < 4; ++r) {
        const int row = b0 + wr + mi * 16 + (lane >> 4) * 4 + r;
        O[(size_t)row * (M_ * OUT_) + m * OUT_ + col] = acc[mi][ni][r] + bs;
      }
    }
  }
}

extern "C" void kernel_launch(void* const* d_in, const int* in_sizes, int n_in,
                              void* d_out, int out_size, void* d_ws, size_t ws_size,
                              hipStream_t stream) {
  const float* X    = (const float*)d_in[0];
  const float* W    = (const float*)d_in[1];
  const float* Bias = (const float*)d_in[2];
  float* O = (float*)d_out;

  dim3 grid(B_ / BM, OUT_ / BN, M_);
  mmlin_kernel<<<grid, dim3(256), 0, stream>>>(X, W, Bias, O);
}

// Round 4
// 153.182 us; speedup vs baseline: 1.1074x; 1.0338x over previous
//
#include <hip/hip_runtime.h>
#include <hip/hip_bf16.h>

// out[b,m,o] = sum_i x[b,m,i] * w[m,i,o] + bias[m,o]
// B=4096, M=8, IN=OUT=512, fp32. Per-mode GEMM via bf16 MFMA, fp32 accum.
// Round 4: prepass packs W -> bf16 pre-swizzled tile-linear chunks in d_ws;
// main kernel stages A (fp32) + B (bf16) via global_load_lds (width 16),
// double-buffered LDS, ONE barrier per K-iter, in-register A conversion.

#define B_   4096
#define M_   8
#define IN_  512
#define OUT_ 512
#define BM   128
#define BN   128
#define BK   32
#define NKT  (IN_ / BK)          // 16 K-tiles
#define WS_NEED (M_ * 4 * 16 * 8192)   // 4 MiB of packed W chunks

typedef __attribute__((ext_vector_type(8))) short  short8;   // 8 bf16
typedef __attribute__((ext_vector_type(4))) float  f32x4;
typedef __attribute__((ext_vector_type(4))) int    i32x4;

#define GLB(p) ((const __attribute__((address_space(1))) void*)(p))
#define LDS(p) ((__attribute__((address_space(3))) void*)(p))

// pack two floats into two RNE-rounded bf16 in one u32 (lo, hi)
static __device__ inline unsigned f2bf2(float lo, float hi) {
  union { float f; unsigned u; } a, b;
  a.f = lo; b.f = hi;
  unsigned ua = a.u + 0x7FFFu + ((a.u >> 16) & 1u);
  unsigned ub = b.u + 0x7FFFu + ((b.u >> 16) & 1u);
  return (ua >> 16) | (ub & 0xFFFF0000u);
}

union pk8 { i32x4 i; short8 s; };

// ---------------------------------------------------------------------------
// Prepass: W[m][i][o] f32  ->  ws chunks. Chunk c = (m*4+nb)*16 + kb (8KB):
// logical (col 0..127, k 0..31) bf16 = W[m][kb*32+k][nb*128+col] at
// phys16 = (col*64 + (k>>3)*16) ^ ((col&7)<<4), byte = phys16 + (k&7)*2.
// Main kernel then streams chunks linearly with global_load_lds.
// ---------------------------------------------------------------------------
extern "C" __global__ __launch_bounds__(256, 2)
void prep_w(const float* __restrict__ W, unsigned char* __restrict__ ws) {
  const int c  = blockIdx.x;          // 0..511
  const int kb = c & 15;
  const int nbm = c >> 4;
  const int nb = nbm & 3;
  const int m  = nbm >> 2;

  __shared__ float tile[32][132];     // [k][col], padded

  const int t  = threadIdx.x;
  // coalesced read: thread t loads 16 floats of row k = t>>3
  {
    const int k  = t >> 3;
    const int n4 = (t & 7) * 16;
    const float* src = W + (size_t)m * (IN_ * OUT_) + (size_t)(kb * 32 + k) * OUT_ + nb * 128 + n4;
#pragma unroll
    for (int i = 0; i < 4; ++i) {
      f32x4 v = *(const f32x4*)(src + i * 4);
      tile[k][n4 + i * 4 + 0] = v[0];
      tile[k][n4 + i * 4 + 1] = v[1];
      tile[k][n4 + i * 4 + 2] = v[2];
      tile[k][n4 + i * 4 + 3] = v[3];
    }
  }
  __syncthreads();

  // write 2 slots of 16B each, pre-swizzled
  unsigned char* out = ws + (size_t)c * 8192;
#pragma unroll
  for (int s = t; s < 512; s += 256) {
    const int col = s >> 2;
    const int k8  = s & 3;
    float f[8];
#pragma unroll
    for (int j = 0; j < 8; ++j) f[j] = tile[k8 * 8 + j][col];
    i32x4 p;
    p[0] = f2bf2(f[0], f[1]); p[1] = f2bf2(f[2], f[3]);
    p[2] = f2bf2(f[4], f[5]); p[3] = f2bf2(f[6], f[7]);
    const int phys = (col * 64 + k8 * 16) ^ ((col & 7) << 4);
    *(i32x4*)(out + phys) = p;
  }
}

// ---------------------------------------------------------------------------
// Main kernel. LDS (48KB): A f32 [2][16KB] @0/@16384, B bf16 [2][8KB] @32768/@40960.
// A LDS image: logical (row 0..127, k4 0..7 [16B units]) at
//   phys = row*128 + (k4 ^ (row&7))*16   (swizzle applied via SOURCE address).
// One __syncthreads per iter: its vmcnt(0) drain is the wait for tile t's
// global_load_lds issued one iteration earlier.
// ---------------------------------------------------------------------------
extern "C" __global__ __launch_bounds__(256, 3)
void mmlin_main(const float* __restrict__ X, const unsigned char* __restrict__ Wp,
                const float* __restrict__ Bias, float* __restrict__ O) {
  __shared__ unsigned char lds[49152];

  const int t = threadIdx.x, l = t & 63, w = t >> 6;
  const int b0 = blockIdx.x * BM;
  const int nb = blockIdx.y;
  const int n0 = nb * BN;
  const int m  = blockIdx.z;

  // ---- A staging: 16 wave-issues of 1KB (8 rows x 128B); wave w does j=w*4..w*4+3.
  // lane l: row_in = l>>3, k4 = l&7; source k4 pre-swizzled: k4_logical = (l&7)^(l>>3).
  const char* Xb = (const char*)X;
  const char* a_src[4];
  int a_dst[4];
#pragma unroll
  for (int i = 0; i < 4; ++i) {
    const int j = w * 4 + i;
    a_src[i] = Xb + (size_t)(b0 + j * 8 + (l >> 3)) * (M_ * IN_ * 4)
             + m * (IN_ * 4)
             + (((l & 7) ^ (l >> 3)) << 4);
    a_dst[i] = j * 1024 + l * 16;
  }
  // ---- B staging: 8 wave-issues of 1KB, purely sequential from packed chunk.
  const unsigned char* b_src = Wp + (size_t)((m * 4 + nb) * 16) * 8192 + (w * 2) * 1024 + l * 16;
  const int b_dst = 32768 + (w * 2) * 1024 + l * 16;

  // ---- fragment read offsets
  const int wr = (w >> 1) * 64, wc = (w & 1) * 64;
  const int fr = l & 15, g = l >> 4;
  int aoff0[4], aoff1[4], boff[4];
#pragma unroll
  for (int mi = 0; mi < 4; ++mi) {
    const int row = wr + mi * 16 + fr;
    aoff0[mi] = row * 128 + (((2 * g)     ^ (row & 7)) << 4);
    aoff1[mi] = row * 128 + (((2 * g + 1) ^ (row & 7)) << 4);
  }
#pragma unroll
  for (int ni = 0; ni < 4; ++ni) {
    const int col = wc + ni * 16 + fr;
    boff[ni] = 32768 + ((col * 64 + g * 16) ^ ((col & 7) << 4));
  }

  f32x4 acc[4][4] = {};

  // ---- prologue: issue tile 0 into buf 0
#pragma unroll
  for (int i = 0; i < 4; ++i)
    __builtin_amdgcn_global_load_lds(GLB(a_src[i]), LDS(lds + a_dst[i]), 16, 0, 0);
#pragma unroll
  for (int i = 0; i < 2; ++i)
    __builtin_amdgcn_global_load_lds(GLB(b_src + i * 1024), LDS(lds + b_dst + i * 1024), 16, 0, 0);

  for (int kt = 0; kt < NKT; ++kt) {
    __syncthreads();                 // vmcnt(0)+lgkmcnt(0)+barrier: tile kt landed everywhere
    const int cur = kt & 1;
    const int nxt = cur ^ 1;

    if (kt + 1 < NKT) {              // fire-and-forget tile kt+1 into other buffer
#pragma unroll
      for (int i = 0; i < 4; ++i)
        __builtin_amdgcn_global_load_lds(GLB(a_src[i] + (kt + 1) * (BK * 4)),
                                         LDS(lds + nxt * 16384 + a_dst[i]), 16, 0, 0);
#pragma unroll
      for (int i = 0; i < 2; ++i)
        __builtin_amdgcn_global_load_lds(GLB(b_src + (size_t)(kt + 1) * 8192 + i * 1024),
                                         LDS(lds + nxt * 8192 + b_dst + i * 1024), 16, 0, 0);
    }

    const unsigned char* A  = lds + cur * 16384;
    const unsigned char* Bb = lds + cur * 8192;   // boff already holds +32768

    short8 af[4], bf[4];
#pragma unroll
    for (int mi = 0; mi < 4; ++mi) {
      f32x4 q0 = *(const f32x4*)(A + aoff0[mi]);
      f32x4 q1 = *(const f32x4*)(A + aoff1[mi]);
      pk8 p;
      p.i[0] = f2bf2(q0[0], q0[1]); p.i[1] = f2bf2(q0[2], q0[3]);
      p.i[2] = f2bf2(q1[0], q1[1]); p.i[3] = f2bf2(q1[2], q1[3]);
      af[mi] = p.s;
    }
#pragma unroll
    for (int ni = 0; ni < 4; ++ni)
      bf[ni] = *(const short8*)(Bb + boff[ni]);

#pragma unroll
    for (int mi = 0; mi < 4; ++mi)
#pragma unroll
      for (int ni = 0; ni < 4; ++ni)
        acc[mi][ni] = __builtin_amdgcn_mfma_f32_16x16x32_bf16(
            af[mi], bf[ni], acc[mi][ni], 0, 0, 0);
  }

  // ---- epilogue: D layout col = lane&15, row = g*4 + r
#pragma unroll
  for (int ni = 0; ni < 4; ++ni) {
    const int col = n0 + wc + ni * 16 + fr;
    const float bs = Bias[m * OUT_ + col];
#pragma unroll
    for (int mi = 0; mi < 4; ++mi) {
#pragma unroll
      for (int r = 0; r < 4; ++r) {
        const int row = b0 + wr + mi * 16 + g * 4 + r;
        O[(size_t)row * (M_ * OUT_) + m * OUT_ + col] = acc[mi][ni][r] + bs;
      }
    }
  }
}

// ---------------------------------------------------------------------------
// Fallback (round-3 kernel, known-correct) if ws_size is too small.
// ---------------------------------------------------------------------------
extern "C" __global__ __launch_bounds__(256, 2)
void mmlin_fallback(const float* __restrict__ X, const float* __restrict__ W,
                    const float* __restrict__ Bias, float* __restrict__ O) {
  __shared__ unsigned char lds[16384];
  const int t = threadIdx.x;
  const int lane = t & 63;
  const int w = t >> 6;
  const int b0 = blockIdx.x * BM;
  const int n0 = blockIdx.y * BN;
  const int m  = blockIdx.z;

  const int ar  = t >> 1;
  const int ac0 = (t & 1) * 16;
  const float* aptr = X + (size_t)(b0 + ar) * (M_ * IN_) + m * IN_ + ac0;
  const int swzA  = (ar & 7) << 4;
  const int a_st0 = (ar * 64 + ac0 * 2)      ^ swzA;
  const int a_st1 = (ar * 64 + ac0 * 2 + 16) ^ swzA;

  const int bc  = t & 127;
  const int bk0 = (t >> 7) * 16;
  const float* bptr = W + (size_t)m * IN_ * OUT_ + (size_t)bk0 * OUT_ + n0 + bc;
  const int swzB  = (bc & 7) << 4;
  const int b_st0 = (8192 + bc * 64 + bk0 * 2)      ^ swzB;
  const int b_st1 = (8192 + bc * 64 + bk0 * 2 + 16) ^ swzB;

  const int wr = (w >> 1) * 64, wc = (w & 1) * 64;
  const int fr = lane & 15;
  const int fkB = (lane >> 4) * 16;

  int a_ld[4], b_ld[4];
#pragma unroll
  for (int mi = 0; mi < 4; ++mi) {
    int row = wr + mi * 16 + fr;
    a_ld[mi] = (row * 64 + fkB) ^ ((row & 7) << 4);
  }
#pragma unroll
  for (int ni = 0; ni < 4; ++ni) {
    int col = wc + ni * 16 + fr;
    b_ld[ni] = (8192 + col * 64 + fkB) ^ ((col & 7) << 4);
  }

  f32x4 acc[4][4] = {};
  f32x4 a_raw[4];
  float b_raw[16];
  {
    const f32x4* ap = (const f32x4*)aptr;
#pragma unroll
    for (int i = 0; i < 4; ++i) a_raw[i] = ap[i];
#pragma unroll
    for (int j = 0; j < 16; ++j) b_raw[j] = bptr[(size_t)j * OUT_];
  }
  i32x4 apk0, apk1, bpk0, bpk1;
  apk0[0] = f2bf2(a_raw[0][0], a_raw[0][1]); apk0[1] = f2bf2(a_raw[0][2], a_raw[0][3]);
  apk0[2] = f2bf2(a_raw[1][0], a_raw[1][1]); apk0[3] = f2bf2(a_raw[1][2], a_raw[1][3]);
  apk1[0] = f2bf2(a_raw[2][0], a_raw[2][1]); apk1[1] = f2bf2(a_raw[2][2], a_raw[2][3]);
  apk1[2] = f2bf2(a_raw[3][0], a_raw[3][1]); apk1[3] = f2bf2(a_raw[3][2], a_raw[3][3]);
  bpk0[0] = f2bf2(b_raw[0],  b_raw[1]);  bpk0[1] = f2bf2(b_raw[2],  b_raw[3]);
  bpk0[2] = f2bf2(b_raw[4],  b_raw[5]);  bpk0[3] = f2bf2(b_raw[6],  b_raw[7]);
  bpk1[0] = f2bf2(b_raw[8],  b_raw[9]);  bpk1[1] = f2bf2(b_raw[10], b_raw[11]);
  bpk1[2] = f2bf2(b_raw[12], b_raw[13]); bpk1[3] = f2bf2(b_raw[14], b_raw[15]);

  for (int kk = 0; kk < IN_; kk += BK) {
    __syncthreads();
    *(i32x4*)(lds + a_st0) = apk0;
    *(i32x4*)(lds + a_st1) = apk1;
    *(i32x4*)(lds + b_st0) = bpk0;
    *(i32x4*)(lds + b_st1) = bpk1;
    __syncthreads();

    const int kn = kk + BK;
    if (kn < IN_) {
      const f32x4* ap = (const f32x4*)(aptr + kn);
#pragma unroll
      for (int i = 0; i < 4; ++i) a_raw[i] = ap[i];
#pragma unroll
      for (int j = 0; j < 16; ++j) b_raw[j] = bptr[(size_t)(kn + j) * OUT_];
    }

    short8 af[4], bf4[4];
#pragma unroll
    for (int mi = 0; mi < 4; ++mi) af[mi]  = *(const short8*)(lds + a_ld[mi]);
#pragma unroll
    for (int ni = 0; ni < 4; ++ni) bf4[ni] = *(const short8*)(lds + b_ld[ni]);

#pragma unroll
    for (int mi = 0; mi < 4; ++mi)
#pragma unroll
      for (int ni = 0; ni < 4; ++ni)
        acc[mi][ni] = __builtin_amdgcn_mfma_f32_16x16x32_bf16(
            af[mi], bf4[ni], acc[mi][ni], 0, 0, 0);

    if (kn < IN_) {
      apk0[0] = f2bf2(a_raw[0][0], a_raw[0][1]); apk0[1] = f2bf2(a_raw[0][2], a_raw[0][3]);
      apk0[2] = f2bf2(a_raw[1][0], a_raw[1][1]); apk0[3] = f2bf2(a_raw[1][2], a_raw[1][3]);
      apk1[0] = f2bf2(a_raw[2][0], a_raw[2][1]); apk1[1] = f2bf2(a_raw[2][2], a_raw[2][3]);
      apk1[2] = f2bf2(a_raw[3][0], a_raw[3][1]); apk1[3] = f2bf2(a_raw[3][2], a_raw[3][3]);
      bpk0[0] = f2bf2(b_raw[0],  b_raw[1]);  bpk0[1] = f2bf2(b_raw[2],  b_raw[3]);
      bpk0[2] = f2bf2(b_raw[4],  b_raw[5]);  bpk0[3] = f2bf2(b_raw[6],  b_raw[7]);
      bpk1[0] = f2bf2(b_raw[8],  b_raw[9]);  bpk1[1] = f2bf2(b_raw[10], b_raw[11]);
      bpk1[2] = f2bf2(b_raw[12], b_raw[13]); bpk1[3] = f2bf2(b_raw[14], b_raw[15]);
    }
  }

#pragma unroll
  for (int ni = 0; ni < 4; ++ni) {
    const int col = n0 + wc + ni * 16 + fr;
    const float bs = Bias[m * OUT_ + col];
#pragma unroll
    for (int mi = 0; mi < 4; ++mi) {
#pragma unroll
      for (int r = 0; r < 4; ++r) {
        const int row = b0 + wr + mi * 16 + (lane >> 4) * 4 + r;
        O[(size_t)row * (M_ * OUT_) + m * OUT_ + col] = acc[mi][ni][r] + bs;
      }
    }
  }
}

extern "C" void kernel_launch(void* const* d_in, const int* in_sizes, int n_in,
                              void* d_out, int out_size, void* d_ws, size_t ws_size,
                              hipStream_t stream) {
  const float* X    = (const float*)d_in[0];
  const float* W    = (const float*)d_in[1];
  const float* Bias = (const float*)d_in[2];
  float* O = (float*)d_out;

  dim3 grid(B_ / BM, OUT_ / BN, M_);
  if (ws_size >= (size_t)WS_NEED) {
    prep_w<<<dim3(512), dim3(256), 0, stream>>>(W, (unsigned char*)d_ws);
    mmlin_main<<<grid, dim3(256), 0, stream>>>(X, (const unsigned char*)d_ws, Bias, O);
  } else {
    mmlin_fallback<<<grid, dim3(256), 0, stream>>>(X, W, Bias, O);
  }
}